// Round 2
// baseline (1057.808 us; speedup 1.0000x reference)
//
#include <hip/hip_runtime.h>
#include <stdint.h>

typedef unsigned short u16;
typedef _Float16 f16;
typedef _Float16 f16x8 __attribute__((ext_vector_type(8)));
typedef _Float16 f16x4 __attribute__((ext_vector_type(4)));
typedef float f32x4 __attribute__((ext_vector_type(4)));

#define AS1 __attribute__((address_space(1)))
#define AS3 __attribute__((address_space(3)))

// async global->LDS, 16B per lane. LDS dest = wave-uniform base + lane*16.
__device__ __forceinline__ void gld16(const void* gp, void* lp) {
    __builtin_amdgcn_global_load_lds((const AS1 void*)gp, (AS3 void*)lp, 16, 0, 0);
}

__device__ __forceinline__ f16 bfbits2h(unsigned b) {
    union { unsigned u; float f; } c; c.u = b << 16; return (f16)c.f;
}
__device__ __forceinline__ float bf2f(u16 b) {
    union { unsigned u; float f; } c; c.u = ((unsigned)b) << 16; return c.f;
}
__device__ __forceinline__ u16 f2bf(float f) {
    union { float f; unsigned u; } c; c.f = f;
    unsigned u = c.u;
    u += 0x7fffu + ((u >> 16) & 1u);
    return (u16)(u >> 16);
}
__device__ __forceinline__ f16x8 cvt_bf8(uint4 r) {
    f16x8 o;
    o[0] = bfbits2h(r.x & 0xffffu); o[1] = bfbits2h(r.x >> 16);
    o[2] = bfbits2h(r.y & 0xffffu); o[3] = bfbits2h(r.y >> 16);
    o[4] = bfbits2h(r.z & 0xffffu); o[5] = bfbits2h(r.z >> 16);
    o[6] = bfbits2h(r.w & 0xffffu); o[7] = bfbits2h(r.w >> 16);
    return o;
}
__device__ __forceinline__ f16x8 cvt_f8(float4 a, float4 b) {
    f16x8 o;
    o[0] = (f16)a.x; o[1] = (f16)a.y; o[2] = (f16)a.z; o[3] = (f16)a.w;
    o[4] = (f16)b.x; o[5] = (f16)b.y; o[6] = (f16)b.z; o[7] = (f16)b.w;
    return o;
}

// ---------------- dtype detector -------------------------------------------
// If inputs are f32, the even-indexed u16 halves are low mantissa bits ->
// random exponents. If bf16, every u16 is a sane N(0,1) bf16.
__global__ __launch_bounds__(256) void detect_dt(const u16* __restrict__ x, int* __restrict__ flag) {
    __shared__ int cnt;
    if (threadIdx.x == 0) cnt = 0;
    __syncthreads();
    int sane = 0;
    #pragma unroll
    for (int i = 0; i < 4; ++i) {
        u16 v = x[(threadIdx.x * 4 + i) * 2];
        int e = (v >> 7) & 0xff;
        if (v == 0 || (e >= 107 && e <= 132)) sane++;
    }
    atomicAdd(&cnt, sane);
    __syncthreads();
    if (threadIdx.x == 0) *flag = (cnt > 512) ? 1 : 0;
}

// ---------------- small conversions ----------------------------------------
__global__ __launch_bounds__(256) void conv_bias(const void* __restrict__ bq, const void* __restrict__ bk,
                                                 const void* __restrict__ bv, const void* __restrict__ bo,
                                                 float* __restrict__ out, const int* __restrict__ flag) {
    int i = blockIdx.x * 256 + threadIdx.x;  // < 7168
    const void* src; int off;
    if (i < 1024)      { src = bq; off = i; }
    else if (i < 2048) { src = bk; off = i - 1024; }
    else if (i < 3072) { src = bv; off = i - 2048; }
    else               { src = bo; off = i - 3072; }
    float v = (*flag) ? bf2f(((const u16*)src)[off]) : ((const float*)src)[off];
    out[i] = v;
}

// transpose weights (R x C, row-major) -> f16 (C x R), flattened tile grid
__global__ __launch_bounds__(256) void transpose_w(const void* __restrict__ Wq, f16* __restrict__ Wqt,
                                                   const void* __restrict__ Wk, f16* __restrict__ Wkt,
                                                   const void* __restrict__ Wv, f16* __restrict__ Wvt,
                                                   const void* __restrict__ Wo, f16* __restrict__ Wot,
                                                   const int* __restrict__ flag) {
    int bid = blockIdx.x;
    const void* in; f16* outp; int R, C, t0;
    if (bid < 1024)      { in = Wq; outp = Wqt; R = 1024; C = 1024; t0 = bid; }
    else if (bid < 5120) { in = Wk; outp = Wkt; R = 4096; C = 1024; t0 = bid - 1024; }
    else if (bid < 9216) { in = Wv; outp = Wvt; R = 4096; C = 1024; t0 = bid - 5120; }
    else                 { in = Wo; outp = Wot; R = 1024; C = 4096; t0 = bid - 9216; }
    int ctiles = C >> 5;
    int rt = t0 / ctiles, ct = t0 - rt * ctiles;
    bool isbf = (*flag != 0);
    __shared__ float tile[32][33];
    int tx = threadIdx.x & 31, ty = threadIdx.x >> 5;
    #pragma unroll
    for (int i2 = 0; i2 < 4; ++i2) {
        size_t idx = (size_t)(rt * 32 + ty + i2 * 8) * C + ct * 32 + tx;
        tile[ty + i2 * 8][tx] = isbf ? bf2f(((const u16*)in)[idx]) : ((const float*)in)[idx];
    }
    __syncthreads();
    #pragma unroll
    for (int i2 = 0; i2 < 4; ++i2) {
        outp[(size_t)(ct * 32 + ty + i2 * 8) * R + rt * 32 + tx] = (f16)tile[tx][ty + i2 * 8];
    }
}

// convert src/val embeddings to f16 (8 elems/thread)
__global__ __launch_bounds__(256) void conv2(const void* __restrict__ a, f16* __restrict__ oa,
                                             const void* __restrict__ b, f16* __restrict__ ob,
                                             int n8, const int* __restrict__ flag) {
    int t = blockIdx.x * 256 + threadIdx.x;
    if (t >= n8) return;
    size_t i = (size_t)t * 8;
    if (*flag) {
        *(f16x8*)(oa + i) = cvt_bf8(*(const uint4*)((const u16*)a + i));
        *(f16x8*)(ob + i) = cvt_bf8(*(const uint4*)((const u16*)b + i));
    } else {
        const float* pa = (const float*)a + i;
        *(f16x8*)(oa + i) = cvt_f8(*(const float4*)pa, *(const float4*)(pa + 4));
        const float* pb = (const float*)b + i;
        *(f16x8*)(ob + i) = cvt_f8(*(const float4*)pb, *(const float4*)(pb + 4));
    }
}

// build [cls ; target] f16 matrix, 16416 x 1024
__global__ __launch_bounds__(256) void build_aq(const void* __restrict__ tgt, const void* __restrict__ cls,
                                                f16* __restrict__ Aq, const int* __restrict__ flag) {
    size_t t = (size_t)blockIdx.x * 256 + threadIdx.x;
    size_t i = t * 8;
    if (i >= (size_t)16416 * 1024) return;
    int d = (int)(i & 1023);
    int row = (int)(i >> 10);
    int b = row / 513;
    int l = row - b * 513;
    const void* base = (l == 0) ? cls : tgt;
    size_t off = (l == 0) ? (size_t)d : ((((size_t)(b * 512 + l - 1)) << 10) + d);
    f16x8 v;
    if (*flag) {
        v = cvt_bf8(*(const uint4*)((const u16*)base + off));
    } else {
        const float* p = (const float*)base + off;
        v = cvt_f8(*(const float4*)p, *(const float4*)(p + 4));
    }
    *(f16x8*)(Aq + i) = v;
}

// ---------------- GEMM core (m97-style): 128x128 tile, BK=64, 4 waves ------
// A: MxK row-major f16. Bt: NxK row-major f16. acc[i][j]: 16x16 C-layout
// (col = lane&15, row = quad*4+reg).
__device__ __forceinline__ void gemm_core(const f16* __restrict__ A, const f16* __restrict__ Bt,
                                          int Aclamp, int K, int m0, int n0,
                                          u16* lA, u16* lB, f32x4 (&acc)[4][4]) {
    const int tid = threadIdx.x;
    const int w = tid >> 6, lane = tid & 63, quad = lane >> 4, l15 = lane & 15;
    const int wr = ((w >> 1) << 6), wc = ((w & 1) << 6);
    const int srow = tid >> 3, scol = (tid & 7) << 3;
    char* lAw = (char*)lA + w * 1024;
    char* lBw = (char*)lB + w * 1024;

    for (int k0 = 0; k0 < K; k0 += 64) {
        #pragma unroll
        for (int q = 0; q < 4; ++q) {
            int ra = m0 + srow + q * 32; if (ra >= Aclamp) ra = Aclamp - 1;
            gld16(A + (size_t)ra * K + k0 + scol, lAw + q * 4096);
            int rb = n0 + srow + q * 32;
            gld16(Bt + (size_t)rb * K + k0 + scol, lBw + q * 4096);
        }
        __syncthreads();
        #pragma unroll
        for (int kk = 0; kk < 64; kk += 32) {
            f16x8 af[4], bf[4];
            #pragma unroll
            for (int i = 0; i < 4; ++i)
                af[i] = *(const f16x8*)((const u16*)lA + (wr + i * 16 + l15) * 64 + kk + quad * 8);
            #pragma unroll
            for (int j = 0; j < 4; ++j)
                bf[j] = *(const f16x8*)((const u16*)lB + (wc + j * 16 + l15) * 64 + kk + quad * 8);
            #pragma unroll
            for (int i = 0; i < 4; ++i)
                #pragma unroll
                for (int j = 0; j < 4; ++j)
                    acc[i][j] = __builtin_amdgcn_mfma_f32_16x16x32_f16(af[i], bf[j], acc[i][j], 0, 0, 0);
        }
        __syncthreads();
    }
}

// EPI 0: final out (bf16 or f32 per flag), EPI 1: f16 row-major (skip rows>=MV)
template <int EPI>
__global__ __launch_bounds__(256) void gemm_f16(const f16* __restrict__ A, const f16* __restrict__ Bt,
                                                const float* __restrict__ bias, void* __restrict__ Cout,
                                                int Aclamp, int MV, int N, int K,
                                                const int* __restrict__ flag) {
    __shared__ u16 lA[128 * 64];
    __shared__ u16 lB[128 * 64];
    f32x4 acc[4][4] = {};
    const int m0 = blockIdx.y * 128, n0 = blockIdx.x * 128;
    gemm_core(A, Bt, Aclamp, K, m0, n0, lA, lB, acc);

    const int tid = threadIdx.x, lane = tid & 63, w = tid >> 6;
    const int quad = lane >> 4, l15 = lane & 15;
    const int wr = ((w >> 1) << 6), wc = ((w & 1) << 6);
    float bj[4];
    #pragma unroll
    for (int j = 0; j < 4; ++j) bj[j] = bias[n0 + wc + j * 16 + l15];

    if (EPI == 0) {
        bool obf = (*flag != 0);
        #pragma unroll
        for (int i = 0; i < 4; ++i)
            #pragma unroll
            for (int j = 0; j < 4; ++j) {
                int c = n0 + wc + j * 16 + l15;
                #pragma unroll
                for (int r = 0; r < 4; ++r) {
                    int row = m0 + wr + i * 16 + quad * 4 + r;
                    if (row < MV) {
                        float v = acc[i][j][r] + bj[j];
                        if (obf) ((u16*)Cout)[(size_t)row * N + c] = f2bf(v);
                        else     ((float*)Cout)[(size_t)row * N + c] = v;
                    }
                }
            }
    } else {
        f16* C = (f16*)Cout;
        #pragma unroll
        for (int i = 0; i < 4; ++i)
            #pragma unroll
            for (int j = 0; j < 4; ++j) {
                int c = n0 + wc + j * 16 + l15;
                #pragma unroll
                for (int r = 0; r < 4; ++r) {
                    int row = m0 + wr + i * 16 + quad * 4 + r;
                    if (row < MV) C[(size_t)row * N + c] = (f16)(acc[i][j][r] + bj[j]);
                }
            }
    }
}

// K and V projections in one launch. z=0: K -> Kb[1024][1024] row-major,
// rows >= 1000 zeroed. z=1: V -> Vt[(h*128+e)][1024] transposed, s >= 1000 zeroed.
__global__ __launch_bounds__(256) void gemm_kv(const f16* __restrict__ srcf, const f16* __restrict__ Wkt,
                                               const float* __restrict__ bkf, f16* __restrict__ Kb,
                                               const f16* __restrict__ valf, const f16* __restrict__ Wvt,
                                               const float* __restrict__ bvf, f16* __restrict__ Vt) {
    const bool isV = (blockIdx.z != 0);
    const f16* A  = isV ? valf : srcf;
    const f16* Bt = isV ? Wvt : Wkt;
    const float* bias = isV ? bvf : bkf;

    __shared__ u16 lA[128 * 64];
    __shared__ u16 lB[128 * 64];
    f32x4 acc[4][4] = {};
    const int m0 = blockIdx.y * 128, n0 = blockIdx.x * 128;
    gemm_core(A, Bt, 1000, 4096, m0, n0, lA, lB, acc);

    const int tid = threadIdx.x, lane = tid & 63, w = tid >> 6;
    const int quad = lane >> 4, l15 = lane & 15;
    const int wr = ((w >> 1) << 6), wc = ((w & 1) << 6);
    float bj[4];
    #pragma unroll
    for (int j = 0; j < 4; ++j) bj[j] = bias[n0 + wc + j * 16 + l15];

    if (!isV) {
        #pragma unroll
        for (int i = 0; i < 4; ++i)
            #pragma unroll
            for (int j = 0; j < 4; ++j) {
                int c = n0 + wc + j * 16 + l15;
                #pragma unroll
                for (int r = 0; r < 4; ++r) {
                    int row = m0 + wr + i * 16 + quad * 4 + r;
                    f16 v = (row < 1000) ? (f16)(acc[i][j][r] + bj[j]) : (f16)0.f;
                    Kb[(size_t)row * 1024 + c] = v;
                }
            }
    } else {
        #pragma unroll
        for (int i = 0; i < 4; ++i)
            #pragma unroll
            for (int j = 0; j < 4; ++j) {
                int c = n0 + wc + j * 16 + l15;
                int rbase = m0 + wr + i * 16 + quad * 4;  // mult of 4; 1000 % 4 == 0
                bool ok = rbase < 1000;
                f16x4 v;
                #pragma unroll
                for (int r = 0; r < 4; ++r) v[r] = ok ? (f16)(acc[i][j][r] + bj[j]) : (f16)0.f;
                *(f16x4*)(Vt + (size_t)c * 1024 + rbase) = v;
            }
    }
}

// ---------------- fused flash attention ------------------------------------
// One block = (b,h) x 128 Q rows. Computes Sc^T = K·Q^T so softmax stats are
// wave-local (wave owns 32 l-columns). S chunk = 64. LDS 48 KB.
__global__ __launch_bounds__(256) void attn(const f16* __restrict__ Qb, const f16* __restrict__ Kb,
                                            const f16* __restrict__ Vtb, f16* __restrict__ Ob) {
    const int tid = threadIdx.x;
    const int w = tid >> 6, lane = tid & 63, quad = lane >> 4, l15 = lane & 15;
    const int qt = blockIdx.x;         // 0..4
    const int bh = blockIdx.y;         // 0..255
    const int b = bh >> 3, h = bh & 7;
    const int l0 = qt * 128;

    __shared__ u16 lK[64 * 128];   // [s][e]
    __shared__ u16 lV[128 * 64];   // [e][s]
    __shared__ u16 lP[128 * 64];   // [l][s]

    // Q fragments (B operand: n=l, k=e), pre-scaled by 1/sqrt(E)
    f16x8 qf[2][4];
    #pragma unroll
    for (int j = 0; j < 2; ++j) {
        int lq = l0 + w * 32 + j * 16 + l15; if (lq > 512) lq = 512;
        const f16* qp = Qb + (((size_t)(b * 513 + lq)) << 10) + (h << 7);
        #pragma unroll
        for (int ks = 0; ks < 4; ++ks) {
            f16x8 v = *(const f16x8*)(qp + ks * 32 + quad * 8);
            qf[j][ks] = v * (f16)0.08838834764831845f;
        }
    }

    f32x4 o[2][8] = {};
    float m_run[2] = {-INFINITY, -INFINITY};
    float l_run[2] = {0.f, 0.f};
    const f32x4 vzero = {0.f, 0.f, 0.f, 0.f};

    const f16* kg = Kb + (((size_t)(tid >> 4)) << 10) + (h << 7) + ((tid & 15) << 3);
    const f16* vg = Vtb + (((size_t)(h * 128 + (tid >> 3))) << 10) + ((tid & 7) << 3);

    for (int c = 0; c < 16; ++c) {
        const int s0 = c * 64;
        #pragma unroll
        for (int q = 0; q < 4; ++q) {
            gld16(kg + (((size_t)(q * 16)) << 10), (char*)lK + w * 1024 + q * 4096);
            gld16(vg + (((size_t)(q * 32)) << 10), (char*)lV + w * 1024 + q * 4096);
        }
        __syncthreads();

        // Sc^T tile: rows s (64), this wave's cols l (32)
        f32x4 sc[4][2];
        #pragma unroll
        for (int i = 0; i < 4; ++i) { sc[i][0] = vzero; sc[i][1] = vzero; }
        #pragma unroll
        for (int ks = 0; ks < 4; ++ks) {
            f16x8 af[4];
            #pragma unroll
            for (int i = 0; i < 4; ++i)
                af[i] = *(const f16x8*)((const u16*)lK + (i * 16 + l15) * 128 + ks * 32 + quad * 8);
            #pragma unroll
            for (int i = 0; i < 4; ++i)
                #pragma unroll
                for (int j = 0; j < 2; ++j)
                    sc[i][j] = __builtin_amdgcn_mfma_f32_16x16x32_f16(af[i], qf[j][ks], sc[i][j], 0, 0, 0);
        }

        if (s0 + 64 > 1000) {  // mask padded keys (only last chunk)
            #pragma unroll
            for (int i = 0; i < 4; ++i)
                #pragma unroll
                for (int r = 0; r < 4; ++r)
                    if (s0 + i * 16 + quad * 4 + r >= 1000) { sc[i][0][r] = -1e30f; sc[i][1][r] = -1e30f; }
        }

        // online softmax, per-column (l) stats; write P to LDS [l][s] as f16
        float alphaj[2];
        #pragma unroll
        for (int j = 0; j < 2; ++j) {
            float mx = -1e30f;
            #pragma unroll
            for (int i = 0; i < 4; ++i)
                #pragma unroll
                for (int r = 0; r < 4; ++r) mx = fmaxf(mx, sc[i][j][r]);
            mx = fmaxf(mx, __shfl_xor(mx, 16));
            mx = fmaxf(mx, __shfl_xor(mx, 32));
            float mnew = fmaxf(m_run[j], mx);
            float al = __expf(m_run[j] - mnew);
            m_run[j] = mnew;
            alphaj[j] = al;
            float sm = 0.f;
            #pragma unroll
            for (int i = 0; i < 4; ++i) {
                f16x4 pv;
                #pragma unroll
                for (int r = 0; r < 4; ++r) {
                    float p = __expf(sc[i][j][r] - mnew);
                    sm += p;
                    pv[r] = (f16)p;
                }
                *(f16x4*)(lP + (size_t)(w * 32 + j * 16 + l15) * 64 + i * 16 + quad * 4) = pv;
            }
            sm += __shfl_xor(sm, 16);
            sm += __shfl_xor(sm, 32);
            l_run[j] = l_run[j] * al + sm;
        }

        // rescale O accumulator (alpha per O-row via lane shuffle)
        #pragma unroll
        for (int mt = 0; mt < 2; ++mt)
            #pragma unroll
            for (int r = 0; r < 4; ++r) {
                float ar = __shfl(alphaj[mt], quad * 4 + r);
                #pragma unroll
                for (int et = 0; et < 8; ++et) o[mt][et][r] *= ar;
            }

        // PV: O[l][e] += P[l][s] * Vt[e][s]
        #pragma unroll
        for (int ks = 0; ks < 2; ++ks) {
            f16x8 ap[2], bv[8];
            #pragma unroll
            for (int mt = 0; mt < 2; ++mt)
                ap[mt] = *(const f16x8*)((const u16*)lP + (w * 32 + mt * 16 + l15) * 64 + ks * 32 + quad * 8);
            #pragma unroll
            for (int et = 0; et < 8; ++et)
                bv[et] = *(const f16x8*)((const u16*)lV + (et * 16 + l15) * 64 + ks * 32 + quad * 8);
            #pragma unroll
            for (int mt = 0; mt < 2; ++mt)
                #pragma unroll
                for (int et = 0; et < 8; ++et)
                    o[mt][et] = __builtin_amdgcn_mfma_f32_16x16x32_f16(ap[mt], bv[et], o[mt][et], 0, 0, 0);
        }
        __syncthreads();

        kg += (size_t)64 << 10;
        vg += 64;
    }

    // normalize and store
    #pragma unroll
    for (int mt = 0; mt < 2; ++mt) {
        float rinv = 1.0f / l_run[mt];
        #pragma unroll
        for (int r = 0; r < 4; ++r) {
            float rr = __shfl(rinv, quad * 4 + r);
            int lg = l0 + w * 32 + mt * 16 + quad * 4 + r;
            if (lg < 513) {
                f16* op = Ob + (((size_t)(b * 513 + lg)) << 10) + (h << 7);
                #pragma unroll
                for (int et = 0; et < 8; ++et)
                    op[et * 16 + l15] = (f16)(o[mt][et][r] * rr);
            }
        }
    }
}

// ---------------- launcher --------------------------------------------------
// Memory plan: intermediates that die before the final GEMM live in d_out
// (guaranteed >= 16416*4096*2 = 134.5 MB; peak scratch use 100.4 MB).
// d_ws holds only what must coexist with the final GEMM (~48.3 MB).
extern "C" void kernel_launch(void* const* d_in, const int* in_sizes, int n_in,
                              void* d_out, int out_size, void* d_ws, size_t ws_size,
                              hipStream_t stream) {
    // ---- ws layout (48.3 MB) ----
    size_t off = 0;
    char* base = (char*)d_ws;
    auto alloc = [&](size_t bytes) {
        void* p = base + off;
        off += (bytes + 255) & ~(size_t)255;
        return p;
    };
    int*   flagp = (int*)alloc(256);
    float* biasf = (float*)alloc(7168 * 4);                    // bq|bk|bv|bo as f32
    f16* Wqt = (f16*)alloc((size_t)1024 * 1024 * 2);           // 2.1 MB
    f16* Wot = (f16*)alloc((size_t)4096 * 1024 * 2);           // 8.4 MB
    f16* Kb  = (f16*)alloc((size_t)1024 * 1024 * 2);           // 2.1 MB
    f16* Vtb = (f16*)alloc((size_t)1024 * 1024 * 2);           // 2.1 MB
    f16* Ob  = (f16*)alloc((size_t)16416 * 1024 * 2);          // 33.6 MB

    // ---- d_out scratch layout (byte offsets; all dead before final GEMM) ----
    char* ob = (char*)d_out;
    f16* Aq   = (f16*)(ob + 0);                                // 33,619,968 B
    f16* Qb   = (f16*)(ob + 33619968);                         // 33,619,968 B
    f16* srcf = (f16*)(ob + 67239936);                         //  8,192,000 B
    f16* valf = (f16*)(ob + 75431936);                         //  8,192,000 B
    f16* Wkt  = (f16*)(ob + 83623936);                         //  8,388,608 B
    f16* Wvt  = (f16*)(ob + 92012544);                         //  8,388,608 B -> end 100,401,152

    detect_dt<<<dim3(1), dim3(256), 0, stream>>>((const u16*)d_in[0], flagp);
    conv_bias<<<dim3(28), dim3(256), 0, stream>>>(d_in[4], d_in[6], d_in[8], d_in[10], biasf, flagp);
    transpose_w<<<dim3(13312), dim3(256), 0, stream>>>(d_in[3], Wqt, d_in[5], Wkt, d_in[7], Wvt, d_in[9], Wot, flagp);
    conv2<<<dim3(2000), dim3(256), 0, stream>>>(d_in[1], srcf, d_in[2], valf, 512000, flagp);
    build_aq<<<dim3(8208), dim3(256), 0, stream>>>(d_in[0], d_in[11], Aq, flagp);

    // Q = Aq @ Wq + bq  -> f16 [16416][1024]
    gemm_f16<1><<<dim3(8, 129), dim3(256), 0, stream>>>(Aq, Wqt, biasf + 0, Qb, 16416, 16416, 1024, 1024, flagp);
    // K,V projections (z picks which)
    gemm_kv<<<dim3(8, 8, 2), dim3(256), 0, stream>>>(srcf, Wkt, biasf + 1024, Kb, valf, Wvt, biasf + 2048, Vtb);
    // fused attention -> Ob f16 [16416][1024]
    attn<<<dim3(5, 256), dim3(256), 0, stream>>>(Qb, Kb, Vtb, Ob);
    // out = Ob @ Wo + bo -> d_out (bf16 or f32 per flag); overwrites all scratch
    gemm_f16<0><<<dim3(32, 129), dim3(256), 0, stream>>>(Ob, Wot, biasf + 3072, d_out, 16416, 16416, 4096, 1024, flagp);
}

// Round 3
// 848.786 us; speedup vs baseline: 1.2463x; 1.2463x over previous
//
#include <hip/hip_runtime.h>
#include <stdint.h>

typedef unsigned short u16;
typedef _Float16 f16;
typedef _Float16 f16x8 __attribute__((ext_vector_type(8)));
typedef _Float16 f16x4 __attribute__((ext_vector_type(4)));
typedef float f32x4 __attribute__((ext_vector_type(4)));

#define AS1 __attribute__((address_space(1)))
#define AS3 __attribute__((address_space(3)))

// async global->LDS, 16B per lane. LDS dest = wave-uniform base + lane*16.
__device__ __forceinline__ void gld16(const void* gp, void* lp) {
    __builtin_amdgcn_global_load_lds((const AS1 void*)gp, (AS3 void*)lp, 16, 0, 0);
}

__device__ __forceinline__ f16 bfbits2h(unsigned b) {
    union { unsigned u; float f; } c; c.u = b << 16; return (f16)c.f;
}
__device__ __forceinline__ float bf2f(u16 b) {
    union { unsigned u; float f; } c; c.u = ((unsigned)b) << 16; return c.f;
}
__device__ __forceinline__ u16 f2bf(float f) {
    union { float f; unsigned u; } c; c.f = f;
    unsigned u = c.u;
    u += 0x7fffu + ((u >> 16) & 1u);
    return (u16)(u >> 16);
}
__device__ __forceinline__ f16x8 cvt_bf8(uint4 r) {
    f16x8 o;
    o[0] = bfbits2h(r.x & 0xffffu); o[1] = bfbits2h(r.x >> 16);
    o[2] = bfbits2h(r.y & 0xffffu); o[3] = bfbits2h(r.y >> 16);
    o[4] = bfbits2h(r.z & 0xffffu); o[5] = bfbits2h(r.z >> 16);
    o[6] = bfbits2h(r.w & 0xffffu); o[7] = bfbits2h(r.w >> 16);
    return o;
}
__device__ __forceinline__ f16x8 cvt_f8(float4 a, float4 b) {
    f16x8 o;
    o[0] = (f16)a.x; o[1] = (f16)a.y; o[2] = (f16)a.z; o[3] = (f16)a.w;
    o[4] = (f16)b.x; o[5] = (f16)b.y; o[6] = (f16)b.z; o[7] = (f16)b.w;
    return o;
}

// ---------------- dtype detector -------------------------------------------
__global__ __launch_bounds__(256) void detect_dt(const u16* __restrict__ x, int* __restrict__ flag) {
    __shared__ int cnt;
    if (threadIdx.x == 0) cnt = 0;
    __syncthreads();
    int sane = 0;
    #pragma unroll
    for (int i = 0; i < 4; ++i) {
        u16 v = x[(threadIdx.x * 4 + i) * 2];
        int e = (v >> 7) & 0xff;
        if (v == 0 || (e >= 107 && e <= 132)) sane++;
    }
    atomicAdd(&cnt, sane);
    __syncthreads();
    if (threadIdx.x == 0) *flag = (cnt > 512) ? 1 : 0;
}

// ---------------- small conversions ----------------------------------------
__global__ __launch_bounds__(256) void conv_bias(const void* __restrict__ bq, const void* __restrict__ bk,
                                                 const void* __restrict__ bv, const void* __restrict__ bo,
                                                 float* __restrict__ out, const int* __restrict__ flag) {
    int i = blockIdx.x * 256 + threadIdx.x;  // < 7168
    const void* src; int off;
    if (i < 1024)      { src = bq; off = i; }
    else if (i < 2048) { src = bk; off = i - 1024; }
    else if (i < 3072) { src = bv; off = i - 2048; }
    else               { src = bo; off = i - 3072; }
    float v = (*flag) ? bf2f(((const u16*)src)[off]) : ((const float*)src)[off];
    out[i] = v;
}

// transpose weights (R x C, row-major) -> f16 (C x R), flattened tile grid
__global__ __launch_bounds__(256) void transpose_w(const void* __restrict__ Wq, f16* __restrict__ Wqt,
                                                   const void* __restrict__ Wk, f16* __restrict__ Wkt,
                                                   const void* __restrict__ Wv, f16* __restrict__ Wvt,
                                                   const void* __restrict__ Wo, f16* __restrict__ Wot,
                                                   const int* __restrict__ flag) {
    int bid = blockIdx.x;
    const void* in; f16* outp; int R, C, t0;
    if (bid < 1024)      { in = Wq; outp = Wqt; R = 1024; C = 1024; t0 = bid; }
    else if (bid < 5120) { in = Wk; outp = Wkt; R = 4096; C = 1024; t0 = bid - 1024; }
    else if (bid < 9216) { in = Wv; outp = Wvt; R = 4096; C = 1024; t0 = bid - 5120; }
    else                 { in = Wo; outp = Wot; R = 1024; C = 4096; t0 = bid - 9216; }
    int ctiles = C >> 5;
    int rt = t0 / ctiles, ct = t0 - rt * ctiles;
    bool isbf = (*flag != 0);
    __shared__ float tile[32][33];
    int tx = threadIdx.x & 31, ty = threadIdx.x >> 5;
    #pragma unroll
    for (int i2 = 0; i2 < 4; ++i2) {
        size_t idx = (size_t)(rt * 32 + ty + i2 * 8) * C + ct * 32 + tx;
        tile[ty + i2 * 8][tx] = isbf ? bf2f(((const u16*)in)[idx]) : ((const float*)in)[idx];
    }
    __syncthreads();
    #pragma unroll
    for (int i2 = 0; i2 < 4; ++i2) {
        outp[(size_t)(ct * 32 + ty + i2 * 8) * R + rt * 32 + tx] = (f16)tile[tx][ty + i2 * 8];
    }
}

// convert src/val embeddings to f16 (8 elems/thread)
__global__ __launch_bounds__(256) void conv2(const void* __restrict__ a, f16* __restrict__ oa,
                                             const void* __restrict__ b, f16* __restrict__ ob,
                                             int n8, const int* __restrict__ flag) {
    int t = blockIdx.x * 256 + threadIdx.x;
    if (t >= n8) return;
    size_t i = (size_t)t * 8;
    if (*flag) {
        *(f16x8*)(oa + i) = cvt_bf8(*(const uint4*)((const u16*)a + i));
        *(f16x8*)(ob + i) = cvt_bf8(*(const uint4*)((const u16*)b + i));
    } else {
        const float* pa = (const float*)a + i;
        *(f16x8*)(oa + i) = cvt_f8(*(const float4*)pa, *(const float4*)(pa + 4));
        const float* pb = (const float*)b + i;
        *(f16x8*)(ob + i) = cvt_f8(*(const float4*)pb, *(const float4*)(pb + 4));
    }
}

// build [cls ; target] f16 matrix, 16416 x 1024
__global__ __launch_bounds__(256) void build_aq(const void* __restrict__ tgt, const void* __restrict__ cls,
                                                f16* __restrict__ Aq, const int* __restrict__ flag) {
    size_t t = (size_t)blockIdx.x * 256 + threadIdx.x;
    size_t i = t * 8;
    if (i >= (size_t)16416 * 1024) return;
    int d = (int)(i & 1023);
    int row = (int)(i >> 10);
    int b = row / 513;
    int l = row - b * 513;
    const void* base = (l == 0) ? cls : tgt;
    size_t off = (l == 0) ? (size_t)d : ((((size_t)(b * 512 + l - 1)) << 10) + d);
    f16x8 v;
    if (*flag) {
        v = cvt_bf8(*(const uint4*)((const u16*)base + off));
    } else {
        const float* p = (const float*)base + off;
        v = cvt_f8(*(const float4*)p, *(const float4*)(p + 4));
    }
    *(f16x8*)(Aq + i) = v;
}

// ---------------- GEMM core: 128x128 tile, BK=64, 4 waves, XOR-swizzled LDS -
// LDS tile layout: row r (128B = 8 16B-blocks), global block b stored at LDS
// block b ^ (r&7). Staging permutes the SOURCE column per lane; readers XOR
// the block index with (row&7). Kills stride-128B bank conflicts.
__device__ __forceinline__ void gemm_core(const f16* __restrict__ A, const f16* __restrict__ Bt,
                                          int Aclamp, int K, int m0, int n0,
                                          u16* lA, u16* lB, f32x4 (&acc)[4][4]) {
    const int tid = threadIdx.x;
    const int w = tid >> 6, lane = tid & 63, quad = lane >> 4, l15 = lane & 15;
    const int wr = ((w >> 1) << 6), wc = ((w & 1) << 6);
    const int srow = tid >> 3;                              // LDS row (mod 32 per q-step)
    const int scol = (((tid & 7) ^ ((tid >> 3) & 7)) << 3); // swizzled source col (u16)
    const int sw7 = l15 & 7;
    char* lAw = (char*)lA + w * 1024;
    char* lBw = (char*)lB + w * 1024;

    for (int k0 = 0; k0 < K; k0 += 64) {
        #pragma unroll
        for (int q = 0; q < 4; ++q) {
            int ra = m0 + srow + q * 32; if (ra >= Aclamp) ra = Aclamp - 1;
            gld16(A + (size_t)ra * K + k0 + scol, lAw + q * 4096);
            int rb = n0 + srow + q * 32;
            gld16(Bt + (size_t)rb * K + k0 + scol, lBw + q * 4096);
        }
        __syncthreads();
        #pragma unroll
        for (int kk2 = 0; kk2 < 2; ++kk2) {
            f16x8 af[4], bf[4];
            #pragma unroll
            for (int i = 0; i < 4; ++i)
                af[i] = *(const f16x8*)(lA + (size_t)(wr + i * 16 + l15) * 64 + (((kk2 * 4 + quad) ^ sw7) << 3));
            #pragma unroll
            for (int j = 0; j < 4; ++j)
                bf[j] = *(const f16x8*)(lB + (size_t)(wc + j * 16 + l15) * 64 + (((kk2 * 4 + quad) ^ sw7) << 3));
            #pragma unroll
            for (int i = 0; i < 4; ++i)
                #pragma unroll
                for (int j = 0; j < 4; ++j)
                    acc[i][j] = __builtin_amdgcn_mfma_f32_16x16x32_f16(af[i], bf[j], acc[i][j], 0, 0, 0);
        }
        __syncthreads();
    }
}

// EPI 0: final out (bf16 or f32 per flag), EPI 1: f16 row-major (skip rows>=MV)
template <int EPI>
__global__ __launch_bounds__(256) void gemm_f16(const f16* __restrict__ A, const f16* __restrict__ Bt,
                                                const float* __restrict__ bias, void* __restrict__ Cout,
                                                int Aclamp, int MV, int N, int K,
                                                const int* __restrict__ flag) {
    __shared__ u16 lA[128 * 64];
    __shared__ u16 lB[128 * 64];
    f32x4 acc[4][4] = {};
    const int m0 = blockIdx.y * 128, n0 = blockIdx.x * 128;
    gemm_core(A, Bt, Aclamp, K, m0, n0, lA, lB, acc);

    const int tid = threadIdx.x, lane = tid & 63, w = tid >> 6;
    const int quad = lane >> 4, l15 = lane & 15;
    const int wr = ((w >> 1) << 6), wc = ((w & 1) << 6);
    float bj[4];
    #pragma unroll
    for (int j = 0; j < 4; ++j) bj[j] = bias[n0 + wc + j * 16 + l15];

    if (EPI == 0) {
        bool obf = (*flag != 0);
        #pragma unroll
        for (int i = 0; i < 4; ++i)
            #pragma unroll
            for (int j = 0; j < 4; ++j) {
                int c = n0 + wc + j * 16 + l15;
                #pragma unroll
                for (int r = 0; r < 4; ++r) {
                    int row = m0 + wr + i * 16 + quad * 4 + r;
                    if (row < MV) {
                        float v = acc[i][j][r] + bj[j];
                        if (obf) ((u16*)Cout)[(size_t)row * N + c] = f2bf(v);
                        else     ((float*)Cout)[(size_t)row * N + c] = v;
                    }
                }
            }
    } else {
        f16* C = (f16*)Cout;
        #pragma unroll
        for (int i = 0; i < 4; ++i)
            #pragma unroll
            for (int j = 0; j < 4; ++j) {
                int c = n0 + wc + j * 16 + l15;
                #pragma unroll
                for (int r = 0; r < 4; ++r) {
                    int row = m0 + wr + i * 16 + quad * 4 + r;
                    if (row < MV) C[(size_t)row * N + c] = (f16)(acc[i][j][r] + bj[j]);
                }
            }
    }
}

// K and V projections in one launch. z=0: K -> Kb[1024][1024] row-major,
// rows >= 1000 zeroed. z=1: V -> Vt[(h*128+e)][1024] transposed, s >= 1000 zeroed.
__global__ __launch_bounds__(256) void gemm_kv(const f16* __restrict__ srcf, const f16* __restrict__ Wkt,
                                               const float* __restrict__ bkf, f16* __restrict__ Kb,
                                               const f16* __restrict__ valf, const f16* __restrict__ Wvt,
                                               const float* __restrict__ bvf, f16* __restrict__ Vt) {
    const bool isV = (blockIdx.z != 0);
    const f16* A  = isV ? valf : srcf;
    const f16* Bt = isV ? Wvt : Wkt;
    const float* bias = isV ? bvf : bkf;

    __shared__ u16 lA[128 * 64];
    __shared__ u16 lB[128 * 64];
    f32x4 acc[4][4] = {};
    const int m0 = blockIdx.y * 128, n0 = blockIdx.x * 128;
    gemm_core(A, Bt, 1000, 4096, m0, n0, lA, lB, acc);

    const int tid = threadIdx.x, lane = tid & 63, w = tid >> 6;
    const int quad = lane >> 4, l15 = lane & 15;
    const int wr = ((w >> 1) << 6), wc = ((w & 1) << 6);
    float bj[4];
    #pragma unroll
    for (int j = 0; j < 4; ++j) bj[j] = bias[n0 + wc + j * 16 + l15];

    if (!isV) {
        #pragma unroll
        for (int i = 0; i < 4; ++i)
            #pragma unroll
            for (int j = 0; j < 4; ++j) {
                int c = n0 + wc + j * 16 + l15;
                #pragma unroll
                for (int r = 0; r < 4; ++r) {
                    int row = m0 + wr + i * 16 + quad * 4 + r;
                    f16 v = (row < 1000) ? (f16)(acc[i][j][r] + bj[j]) : (f16)0.f;
                    Kb[(size_t)row * 1024 + c] = v;
                }
            }
    } else {
        #pragma unroll
        for (int i = 0; i < 4; ++i)
            #pragma unroll
            for (int j = 0; j < 4; ++j) {
                int c = n0 + wc + j * 16 + l15;
                int rbase = m0 + wr + i * 16 + quad * 4;  // mult of 4; 1000 % 4 == 0
                bool ok = rbase < 1000;
                f16x4 v;
                #pragma unroll
                for (int r = 0; r < 4; ++r) v[r] = ok ? (f16)(acc[i][j][r] + bj[j]) : (f16)0.f;
                *(f16x4*)(Vt + (size_t)c * 1024 + rbase) = v;
            }
    }
}

// ---------------- fused flash attention ------------------------------------
// One block = (b,h) x 128 Q rows. Sc^T = K·Q^T so softmax stats are wave-local
// (wave owns 32 l-columns). S chunk = 64. LDS 48 KB, all tiles XOR-swizzled.
__global__ __launch_bounds__(256) void attn(const f16* __restrict__ Qb, const f16* __restrict__ Kb,
                                            const f16* __restrict__ Vtb, f16* __restrict__ Ob) {
    const int tid = threadIdx.x;
    const int w = tid >> 6, lane = tid & 63, quad = lane >> 4, l15 = lane & 15;
    const int sw7 = l15 & 7;
    const int qt = blockIdx.x;         // 0..4
    const int bh = blockIdx.y;         // 0..255
    const int b = bh >> 3, h = bh & 7;
    const int l0 = qt * 128;

    __shared__ u16 lK[64 * 128];   // [s][e], 16 blocks/row, swizzled
    __shared__ u16 lV[128 * 64];   // [e][s], 8 blocks/row, swizzled
    __shared__ u16 lP[128 * 64];   // [l][s], 8 blocks/row, swizzled

    // Q fragments (B operand: n=l, k=e), pre-scaled by 1/sqrt(E)
    f16x8 qf[2][4];
    #pragma unroll
    for (int j = 0; j < 2; ++j) {
        int lq = l0 + w * 32 + j * 16 + l15; if (lq > 512) lq = 512;
        const f16* qp = Qb + (((size_t)(b * 513 + lq)) << 10) + (h << 7);
        #pragma unroll
        for (int ks = 0; ks < 4; ++ks) {
            f16x8 v = *(const f16x8*)(qp + ks * 32 + quad * 8);
            qf[j][ks] = v * (f16)0.08838834764831845f;
        }
    }

    f32x4 o[2][8] = {};
    float m_run[2] = {-INFINITY, -INFINITY};
    float l_run[2] = {0.f, 0.f};
    const f32x4 vzero = {0.f, 0.f, 0.f, 0.f};

    // staging pointers with swizzled source columns:
    // lK: LDS row = tid>>4 (+q*16), block c = tid&15 -> fetch global block c ^ (row&7)
    const int kcol = (((tid & 15) ^ ((tid >> 4) & 7)) << 3);
    const f16* kg = Kb + (((size_t)(tid >> 4)) << 10) + (h << 7) + kcol;
    // lV: LDS row = tid>>3 (+q*32), block c = tid&7 -> fetch global block c ^ (row&7)
    const int vcol = (((tid & 7) ^ ((tid >> 3) & 7)) << 3);
    const f16* vg = Vtb + (((size_t)(h * 128 + (tid >> 3))) << 10) + vcol;

    for (int c = 0; c < 16; ++c) {
        const int s0 = c * 64;
        #pragma unroll
        for (int q = 0; q < 4; ++q) {
            gld16(kg + (((size_t)(q * 16)) << 10), (char*)lK + w * 1024 + q * 4096);
            gld16(vg + (((size_t)(q * 32)) << 10), (char*)lV + w * 1024 + q * 4096);
        }
        __syncthreads();

        // Sc^T tile: rows s (64), this wave's cols l (32)
        f32x4 sc[4][2];
        #pragma unroll
        for (int i = 0; i < 4; ++i) { sc[i][0] = vzero; sc[i][1] = vzero; }
        #pragma unroll
        for (int ks = 0; ks < 4; ++ks) {
            f16x8 af[4];
            #pragma unroll
            for (int i = 0; i < 4; ++i)
                af[i] = *(const f16x8*)(lK + (size_t)(i * 16 + l15) * 128 + (((ks * 4 + quad) ^ sw7) << 3));
            #pragma unroll
            for (int i = 0; i < 4; ++i)
                #pragma unroll
                for (int j = 0; j < 2; ++j)
                    sc[i][j] = __builtin_amdgcn_mfma_f32_16x16x32_f16(af[i], qf[j][ks], sc[i][j], 0, 0, 0);
        }

        if (s0 + 64 > 1000) {  // mask padded keys (only last chunk)
            #pragma unroll
            for (int i = 0; i < 4; ++i)
                #pragma unroll
                for (int r = 0; r < 4; ++r)
                    if (s0 + i * 16 + quad * 4 + r >= 1000) { sc[i][0][r] = -1e30f; sc[i][1][r] = -1e30f; }
        }

        // online softmax, per-column (l) stats; write P to LDS [l][s] as f16
        float alphaj[2];
        #pragma unroll
        for (int j = 0; j < 2; ++j) {
            float mx = -1e30f;
            #pragma unroll
            for (int i = 0; i < 4; ++i)
                #pragma unroll
                for (int r = 0; r < 4; ++r) mx = fmaxf(mx, sc[i][j][r]);
            mx = fmaxf(mx, __shfl_xor(mx, 16));
            mx = fmaxf(mx, __shfl_xor(mx, 32));
            float mnew = fmaxf(m_run[j], mx);
            float al = __expf(m_run[j] - mnew);
            m_run[j] = mnew;
            alphaj[j] = al;
            float sm = 0.f;
            #pragma unroll
            for (int i = 0; i < 4; ++i) {
                f16x4 pv;
                #pragma unroll
                for (int r = 0; r < 4; ++r) {
                    float p = __expf(sc[i][j][r] - mnew);
                    sm += p;
                    pv[r] = (f16)p;
                }
                // logical col = i*16 + quad*4 -> block i*2+(quad>>1), sub (quad&1)*4
                *(f16x4*)(lP + (size_t)(w * 32 + j * 16 + l15) * 64
                              + (((i * 2 + (quad >> 1)) ^ sw7) << 3) + ((quad & 1) << 2)) = pv;
            }
            sm += __shfl_xor(sm, 16);
            sm += __shfl_xor(sm, 32);
            l_run[j] = l_run[j] * al + sm;
        }

        // rescale O accumulator (alpha per O-row via lane shuffle)
        #pragma unroll
        for (int mt = 0; mt < 2; ++mt)
            #pragma unroll
            for (int r = 0; r < 4; ++r) {
                float ar = __shfl(alphaj[mt], quad * 4 + r);
                #pragma unroll
                for (int et = 0; et < 8; ++et) o[mt][et][r] *= ar;
            }

        // PV: O[l][e] += P[l][s] * Vt[e][s]
        #pragma unroll
        for (int ks = 0; ks < 2; ++ks) {
            f16x8 ap[2], bv[8];
            #pragma unroll
            for (int mt = 0; mt < 2; ++mt)
                ap[mt] = *(const f16x8*)(lP + (size_t)(w * 32 + mt * 16 + l15) * 64 + (((ks * 4 + quad) ^ sw7) << 3));
            #pragma unroll
            for (int et = 0; et < 8; ++et)
                bv[et] = *(const f16x8*)(lV + (size_t)(et * 16 + l15) * 64 + (((ks * 4 + quad) ^ sw7) << 3));
            #pragma unroll
            for (int mt = 0; mt < 2; ++mt)
                #pragma unroll
                for (int et = 0; et < 8; ++et)
                    o[mt][et] = __builtin_amdgcn_mfma_f32_16x16x32_f16(ap[mt], bv[et], o[mt][et], 0, 0, 0);
        }
        __syncthreads();

        kg += (size_t)64 << 10;
        vg += 64;
    }

    // normalize and store
    #pragma unroll
    for (int mt = 0; mt < 2; ++mt) {
        float rinv = 1.0f / l_run[mt];
        #pragma unroll
        for (int r = 0; r < 4; ++r) {
            float rr = __shfl(rinv, quad * 4 + r);
            int lg = l0 + w * 32 + mt * 16 + quad * 4 + r;
            if (lg < 513) {
                f16* op = Ob + (((size_t)(b * 513 + lg)) << 10) + (h << 7);
                #pragma unroll
                for (int et = 0; et < 8; ++et)
                    op[et * 16 + l15] = (f16)(o[mt][et][r] * rr);
            }
        }
    }
}

// ---------------- launcher --------------------------------------------------
// Memory plan: intermediates that die before the final GEMM live in d_out
// (guaranteed >= 16416*4096*2 = 134.5 MB; peak scratch use 100.4 MB).
// d_ws holds only what must coexist with the final GEMM (~48.3 MB).
extern "C" void kernel_launch(void* const* d_in, const int* in_sizes, int n_in,
                              void* d_out, int out_size, void* d_ws, size_t ws_size,
                              hipStream_t stream) {
    // ---- ws layout (48.3 MB) ----
    size_t off = 0;
    char* base = (char*)d_ws;
    auto alloc = [&](size_t bytes) {
        void* p = base + off;
        off += (bytes + 255) & ~(size_t)255;
        return p;
    };
    int*   flagp = (int*)alloc(256);
    float* biasf = (float*)alloc(7168 * 4);                    // bq|bk|bv|bo as f32
    f16* Wqt = (f16*)alloc((size_t)1024 * 1024 * 2);           // 2.1 MB
    f16* Wot = (f16*)alloc((size_t)4096 * 1024 * 2);           // 8.4 MB
    f16* Kb  = (f16*)alloc((size_t)1024 * 1024 * 2);           // 2.1 MB
    f16* Vtb = (f16*)alloc((size_t)1024 * 1024 * 2);           // 2.1 MB
    f16* Ob  = (f16*)alloc((size_t)16416 * 1024 * 2);          // 33.6 MB

    // ---- d_out scratch layout (byte offsets; all dead before final GEMM) ----
    char* ob = (char*)d_out;
    f16* Aq   = (f16*)(ob + 0);                                // 33,619,968 B
    f16* Qb   = (f16*)(ob + 33619968);                         // 33,619,968 B
    f16* srcf = (f16*)(ob + 67239936);                         //  8,192,000 B
    f16* valf = (f16*)(ob + 75431936);                         //  8,192,000 B
    f16* Wkt  = (f16*)(ob + 83623936);                         //  8,388,608 B
    f16* Wvt  = (f16*)(ob + 92012544);                         //  8,388,608 B -> end 100,401,152

    detect_dt<<<dim3(1), dim3(256), 0, stream>>>((const u16*)d_in[0], flagp);
    conv_bias<<<dim3(28), dim3(256), 0, stream>>>(d_in[4], d_in[6], d_in[8], d_in[10], biasf, flagp);
    transpose_w<<<dim3(13312), dim3(256), 0, stream>>>(d_in[3], Wqt, d_in[5], Wkt, d_in[7], Wvt, d_in[9], Wot, flagp);
    conv2<<<dim3(2000), dim3(256), 0, stream>>>(d_in[1], srcf, d_in[2], valf, 512000, flagp);
    build_aq<<<dim3(8208), dim3(256), 0, stream>>>(d_in[0], d_in[11], Aq, flagp);

    // Q = Aq @ Wq + bq  -> f16 [16416][1024]
    gemm_f16<1><<<dim3(8, 129), dim3(256), 0, stream>>>(Aq, Wqt, biasf + 0, Qb, 16416, 16416, 1024, 1024, flagp);
    // K,V projections (z picks which)
    gemm_kv<<<dim3(8, 8, 2), dim3(256), 0, stream>>>(srcf, Wkt, biasf + 1024, Kb, valf, Wvt, biasf + 2048, Vtb);
    // fused attention -> Ob f16 [16416][1024]
    attn<<<dim3(5, 256), dim3(256), 0, stream>>>(Qb, Kb, Vtb, Ob);
    // out = Ob @ Wo + bo -> d_out (bf16 or f32 per flag); overwrites all scratch
    gemm_f16<0><<<dim3(32, 129), dim3(256), 0, stream>>>(Ob, Wot, biasf + 3072, d_out, 16416, 16416, 4096, 1024, flagp);
}